// Round 4
// baseline (204.328 us; speedup 1.0000x reference)
//
#include <hip/hip_runtime.h>
#include <stdint.h>

typedef unsigned long long u64;
typedef unsigned int u32;
typedef float vf2 __attribute__((ext_vector_type(2)));

constexpr int Ccand = 32;   // candidates per row
constexpr int Evoc  = 512;  // vocab size
constexpr int Tgt   = 64;   // target_size

// ---- xor-partner exchange (round-2 known-good forms) ----------------------
// j=1,2  : DPP quad_perm  (pure VALU, no LDS, no address math)
// j=4..16: ds_swizzle with immediate xor pattern (no address VALU)
// j=32   : bpermute-based __shfl_xor (crosses the 32-lane swizzle boundary)
template<int J>
__device__ __forceinline__ int shx32(int x) {
    if constexpr (J == 1)       return __builtin_amdgcn_update_dpp(0, x, 0xB1, 0xF, 0xF, true); // quad_perm [1,0,3,2]
    else if constexpr (J == 2)  return __builtin_amdgcn_update_dpp(0, x, 0x4E, 0xF, 0xF, true); // quad_perm [2,3,0,1]
    else if constexpr (J <= 16) return __builtin_amdgcn_ds_swizzle(x, (J << 10) | 0x1F);        // BitMode xor
    else                        return __shfl_xor(x, J);
}

// bitonic compare-exchange step; direction masks (lane&K2)==0 / (lane&J)==0 are
// 6 distinct values total -> CSE'd into SGPR masks, step is cmp + s_xnor + cndmask
template<int K2, int J>
__device__ __forceinline__ void cas_f32(float& a, int lane) {
    float o = __int_as_float(shx32<J>(__float_as_int(a)));
    bool keepMax = (((lane & K2) == 0) == ((lane & J) == 0));
    bool g = a > o;
    a = (keepMax == g) ? a : o;
}

template<int K2, int J>
__device__ __forceinline__ void cas_u64(u64& a, int lane) {
    int lo = shx32<J>((int)(u32)a);
    int hi = shx32<J>((int)(u32)(a >> 32));
    u64 o = ((u64)(u32)hi << 32) | (u32)lo;
    bool keepMax = (((lane & K2) == 0) == ((lane & J) == 0));
    bool g = a > o;
    a = (keepMax == g) ? a : o;
}

__device__ __forceinline__ void sort64_desc_f32(float& a, int lane) {
    cas_f32<2,1>(a,lane);
    cas_f32<4,2>(a,lane);   cas_f32<4,1>(a,lane);
    cas_f32<8,4>(a,lane);   cas_f32<8,2>(a,lane);   cas_f32<8,1>(a,lane);
    cas_f32<16,8>(a,lane);  cas_f32<16,4>(a,lane);  cas_f32<16,2>(a,lane);  cas_f32<16,1>(a,lane);
    cas_f32<32,16>(a,lane); cas_f32<32,8>(a,lane);  cas_f32<32,4>(a,lane);  cas_f32<32,2>(a,lane);  cas_f32<32,1>(a,lane);
    cas_f32<64,32>(a,lane); cas_f32<64,16>(a,lane); cas_f32<64,8>(a,lane);  cas_f32<64,4>(a,lane);  cas_f32<64,2>(a,lane); cas_f32<64,1>(a,lane);
}

__device__ __forceinline__ void sort64_desc_u64(u64& a, int lane) {
    cas_u64<2,1>(a,lane);
    cas_u64<4,2>(a,lane);   cas_u64<4,1>(a,lane);
    cas_u64<8,4>(a,lane);   cas_u64<8,2>(a,lane);   cas_u64<8,1>(a,lane);
    cas_u64<16,8>(a,lane);  cas_u64<16,4>(a,lane);  cas_u64<16,2>(a,lane);  cas_u64<16,1>(a,lane);
    cas_u64<32,16>(a,lane); cas_u64<32,8>(a,lane);  cas_u64<32,4>(a,lane);  cas_u64<32,2>(a,lane);  cas_u64<32,1>(a,lane);
    cas_u64<64,32>(a,lane); cas_u64<64,16>(a,lane); cas_u64<64,8>(a,lane);  cas_u64<64,4>(a,lane);  cas_u64<64,2>(a,lane); cas_u64<64,1>(a,lane);
}

// reverse low 16 bits: bit t of result = bit (15-t) of x
__device__ __forceinline__ u32 rev16(u32 x) {
    return __builtin_bitreverse32(x) >> 16;
}

// One wave (64 lanes) per row. Lane l owns cols {4l..4l+3} and {256+4l..+3}.
__global__ __launch_bounds__(256, 8) void cooc_expand(
    const int* __restrict__ cand_ids,
    const float* __restrict__ cand_scores,
    const float* __restrict__ cooc,
    float* __restrict__ out_ids,
    float* __restrict__ out_scores,
    int B)
{
    const int lane = threadIdx.x & 63;
    const int wid  = threadIdx.x >> 6;
    const int row  = blockIdx.x * 4 + wid;
    __shared__ u64 buf[4][64];     // per-wave 64-slot window (2 KB/block)
    __shared__ u32 maskw[4][16];   // per-wave 512-bit candidate bitmap
    if (row >= B) return;   // never taken (B % 4 == 0); no block barriers used

    // ---- load candidates (lanes 0..31); start the LDS candidate bitmap early ----
    if (lane < 16) maskw[wid][lane] = 0u;
    int   my_id = -1;
    float my_s  = 0.0f;
    if (lane < Ccand) {
        my_id = cand_ids[(size_t)row * Ccand + lane];
        my_s  = cand_scores[(size_t)row * Ccand + lane];
    }
    __threadfence_block();  // zero before or (same-wave LDS ordering)
    if (lane < Ccand)
        atomicOr(&maskw[wid][(u32)my_id >> 5], 1u << (my_id & 31));  // idempotent, dups fine

    // ---- all-pairs id compare, SPLIT across wave halves ------------------
    // lane l<32 compares id_l against j=0..15; lane l+32 compares the SAME
    // id (one shfl_xor) against j=16..31. 16 bpermute broadcasts (DS pipe)
    // instead of 32 readlanes (VALU pipe); one shfl_xor recombines masks.
    int pid = __shfl_xor(my_id, 32);              // lanes>=32: id of lane-32
    int qid = (lane < 32) ? my_id : pid;          // id this lane is responsible for
    const int jb4 = (lane < 32) ? 0 : (16 << 2);  // byte addr base of j-range
    u32 acc_eq = 0u, acc_lt = 0u;
    #pragma unroll
    for (int t = 0; t < 16; ++t) {
        int idj = __builtin_amdgcn_ds_bpermute(jb4 + (t << 2), my_id); // id_{jb+t}
        acc_eq = (acc_eq << 1) | (idj == qid ? 1u : 0u);
        acc_lt = (acc_lt << 1) | (idj <  qid ? 1u : 0u);
    }
    // bit t of rev16(acc) corresponds to j = jb + t
    u32 pk = (rev16(acc_eq) << 16) | rev16(acc_lt);
    u32 op = (u32)__shfl_xor((int)pk, 32);        // partner's masks (other j-half)
    // full 32-bit masks over j=0..31 (valid for lanes<32; unused elsewhere)
    u32 eqm = (pk >> 16) | (op & 0xFFFF0000u);
    u32 ltm = (pk & 0xFFFFu) | (op << 16);

    u32 below = (1u << (lane & 31)) - 1u;
    bool alive = (lane < Ccand) && ((eqm & below) == 0u);  // first occurrence of my_id
    u64 aball = __ballot(alive);
    int m  = __popcll(aball);                 // distinct ids (wave-uniform, >=1)
    int rk = __popc(ltm & (u32)aball);        // rank among distinct ids, ascending id

    // ---- exact duplicate-merge (np.add.at ascending-j order) -------------
    // alive lane's own j is the LOWEST set bit of eqm; start from my_s and
    // add later matches ascending via ffs/bpermute. 0 iterations for ~38%
    // of rows, <=2 for nearly all others.
    float smv = my_s;
    u32 rem = alive ? (eqm & ~(1u << (lane & 31))) : 0u;
    while (__any(rem != 0u)) {
        int j = __ffs(rem) - 1;                // lowest set bit (ascending j)
        float sj = __int_as_float(__builtin_amdgcn_ds_bpermute(j << 2, __float_as_int(my_s)));
        smv += (rem != 0u) ? sj : 0.0f;        // +0.0 exact no-op (smv >= +0)
        rem &= rem - 1u;
    }

    int dst = alive ? rk : ((lane < 32) ? (lane + 32) : lane);
    int sorted_id = __builtin_amdgcn_ds_permute(dst << 2, my_id);
    int sorted_sb = __builtin_amdgcn_ds_permute(dst << 2, __float_as_int(smv));

    // ---- accumulation: 2 ids/trip, DEPTH-1 SOFTWARE PIPELINE.
    // Next trip's 4 dwordx4 are issued BEFORE the current trip's FMAs, so
    // the compiler emits a counted vmcnt(4) and the prefetch stays in
    // flight across the back-edge (round-2's unroll-1 loop drained
    // vmcnt(0) every trip). Prefetch indices clamp to m-1 (valid, L1-hot);
    // tail scores are 0 and fma(0,·,acc)==acc bit-exact (acc stays >= +0).
    // FMA order: ids strictly ascending, acc2[0..3] per id — identical
    // association to the round-2 loop (bit-exact).
    vf2 acc2[4];
    acc2[0] = (vf2){0.f, 0.f}; acc2[1] = (vf2){0.f, 0.f};
    acc2[2] = (vf2){0.f, 0.f}; acc2[3] = (vf2){0.f, 0.f};
    const int l4 = lane << 2;
    const int mm1 = m - 1;
    // prologue: ids 0,1 (clamped)
    int p1 = (1 <= mm1) ? 1 : mm1;
    int e0 = __builtin_amdgcn_readlane(sorted_id, 0) & 511;
    int e1 = __builtin_amdgcn_readlane(sorted_id, p1) & 511;
    float s0 = __int_as_float(__builtin_amdgcn_readlane(sorted_sb, 0));
    float s1 = (1 < m) ? __int_as_float(__builtin_amdgcn_readlane(sorted_sb, p1)) : 0.0f;
    const float* rp0 = cooc + ((size_t)e0 << 9);
    const float* rp1 = cooc + ((size_t)e1 << 9);
    float4 a0 = *reinterpret_cast<const float4*>(rp0 + l4);
    float4 a1 = *reinterpret_cast<const float4*>(rp0 + 256 + l4);
    float4 b0 = *reinterpret_cast<const float4*>(rp1 + l4);
    float4 b1 = *reinterpret_cast<const float4*>(rp1 + 256 + l4);
    #pragma unroll 1
    for (int t = 0; t < m; t += 2) {
        // ---- prefetch ids t+2, t+3 (clamped to m-1) ----
        int q0 = (t + 2 <= mm1) ? (t + 2) : mm1;
        int q1 = (t + 3 <= mm1) ? (t + 3) : mm1;
        int f0 = __builtin_amdgcn_readlane(sorted_id, q0) & 511;
        int f1 = __builtin_amdgcn_readlane(sorted_id, q1) & 511;
        float u0 = (t + 2 < m) ? __int_as_float(__builtin_amdgcn_readlane(sorted_sb, q0)) : 0.0f;
        float u1 = (t + 3 < m) ? __int_as_float(__builtin_amdgcn_readlane(sorted_sb, q1)) : 0.0f;
        const float* sp0 = cooc + ((size_t)f0 << 9);
        const float* sp1 = cooc + ((size_t)f1 << 9);
        float4 c0 = *reinterpret_cast<const float4*>(sp0 + l4);
        float4 c1 = *reinterpret_cast<const float4*>(sp0 + 256 + l4);
        float4 d0 = *reinterpret_cast<const float4*>(sp1 + l4);
        float4 d1 = *reinterpret_cast<const float4*>(sp1 + 256 + l4);
        // ---- FMA current two ids (waits vmcnt(4); prefetch in flight) ----
        {
            vf2 sv; sv[0] = s0; sv[1] = s0;
            vf2 x0; x0[0] = a0.x; x0[1] = a0.y;
            vf2 x1; x1[0] = a0.z; x1[1] = a0.w;
            vf2 y0; y0[0] = a1.x; y0[1] = a1.y;
            vf2 y1; y1[0] = a1.z; y1[1] = a1.w;
            acc2[0] = __builtin_elementwise_fma(sv, x0, acc2[0]);
            acc2[1] = __builtin_elementwise_fma(sv, x1, acc2[1]);
            acc2[2] = __builtin_elementwise_fma(sv, y0, acc2[2]);
            acc2[3] = __builtin_elementwise_fma(sv, y1, acc2[3]);
        }
        {
            vf2 sv; sv[0] = s1; sv[1] = s1;
            vf2 x0; x0[0] = b0.x; x0[1] = b0.y;
            vf2 x1; x1[0] = b0.z; x1[1] = b0.w;
            vf2 y0; y0[0] = b1.x; y0[1] = b1.y;
            vf2 y1; y1[0] = b1.z; y1[1] = b1.w;
            acc2[0] = __builtin_elementwise_fma(sv, x0, acc2[0]);
            acc2[1] = __builtin_elementwise_fma(sv, x1, acc2[1]);
            acc2[2] = __builtin_elementwise_fma(sv, y0, acc2[2]);
            acc2[3] = __builtin_elementwise_fma(sv, y1, acc2[3]);
        }
        // ---- rotate (register renaming; no data movement after RA) ----
        s0 = u0; s1 = u1;
        a0 = c0; a1 = c1; b0 = d0; b1 = d1;
    }

    // ---- masked-slot bits from the LDS bitmap (reference: cooc_scores[b,e] = -inf).
    // col c=4l+q -> word l>>3 bit 4(l&7)+q ; col 256+4l+q -> word 8+(l>>3) same bit.
    __threadfence_block();
    u32 wA = maskw[wid][lane >> 3];
    u32 wB = maskw[wid][8 + (lane >> 3)];
    int sh = (lane & 7) << 2;
    u32 mb = ((wA >> sh) & 15u) | (((wB >> sh) & 15u) << 4);

    // ---- original-layout values; masked -> -1.0 (strictly below all) ----
    float v[8];
    v[0] = acc2[0][0]; v[1] = acc2[0][1]; v[2] = acc2[1][0]; v[3] = acc2[1][1];
    v[4] = acc2[2][0]; v[5] = acc2[2][1]; v[6] = acc2[3][0]; v[7] = acc2[3][1];
    #pragma unroll
    for (int j = 0; j < 8; ++j)
        if ((mb >> j) & 1u) v[j] = -1.0f;

    // ---- L32: 32nd largest of per-lane maxima; L32 <= V32 (true 32nd of
    // all 512) and >=32 elements are >= L32, so every top-32 element
    // survives and S_tot >= 32 ----
    float mx8 = v[0];
    #pragma unroll
    for (int j = 1; j < 8; ++j) mx8 = fmaxf(mx8, v[j]);
    float srt = mx8;
    sort64_desc_f32(srt, lane);
    float L32 = __int_as_float(__builtin_amdgcn_readlane(__float_as_int(srt), 31));

    // ---- survivor count + exclusive prefix via ballot/mbcnt (no shfl_up chain) ----
    int cnt = 0;
    #pragma unroll
    for (int j = 0; j < 8; ++j) cnt += (v[j] >= L32) ? 1 : 0;
    int sbase = 0, S_tot = 0;
    #pragma unroll
    for (int b = 0; b < 4; ++b) {
        u64 bal = __ballot(((cnt >> b) & 1) != 0);
        int pc = __builtin_amdgcn_mbcnt_hi((u32)(bal >> 32),
                 __builtin_amdgcn_mbcnt_lo((u32)bal, 0));
        sbase += pc << b;
        S_tot += ((int)__popcll(bal)) << b;
    }

    // ---- chunked scatter + sort + merge-prune over 64-slot windows.
    // Chunk 0 is the whole story for ~99.98% of rows (S_tot <= 64).
    // Keys (valbits<<32 | 511-col) unique; desc u64 order == np stable
    // top-k order (value desc, col asc). ----
    int nchunk = (S_tot + 63) >> 6;   // wave-uniform >= 1
    u64 cur = 0ull;
    #pragma unroll 1
    for (int c = 0; c < nchunk; ++c) {
        const int lo = c << 6;
        // scatter survivors whose slot falls in [lo, lo+64)
        int slot = sbase;
        #pragma unroll
        for (int j = 0; j < 8; ++j) {
            bool s = (v[j] >= L32);
            int  rel = slot - lo;
            if (s && rel >= 0 && rel < 64) {
                int col = (j < 4) ? (l4 + j) : (256 + l4 + (j - 4));
                buf[wid][rel] = ((u64)__float_as_uint(v[j]) << 32) | (u32)(511 - col);
            }
            slot += s ? 1 : 0;
        }
        __threadfence_block();
        u64 nxt = (lo + lane < S_tot) ? buf[wid][lane] : 0ull;
        __threadfence_block();   // reads complete before next chunk's writes
        sort64_desc_u64(nxt, lane);
        if (c == 0) {
            cur = nxt;
        } else {
            u64 o = __shfl_xor(nxt, 63);           // nxt[63-lane]
            cur = (cur >= o) ? cur : o;            // top-64 of 128, bitonic
            cas_u64<64,32>(cur, lane);             // descending cleanup
            cas_u64<64,16>(cur, lane);
            cas_u64<64,8>(cur, lane);
            cas_u64<64,4>(cur, lane);
            cas_u64<64,2>(cur, lane);
            cas_u64<64,1>(cur, lane);
        }
    }
    // lane r now holds rank-r key (r < 32 are the selected top-32)

    // ---- coalesced stores: [orig 32 | selected 32] ----
    int src = (lane >= 32) ? (lane - 32) : 0;
    u64 kk = __shfl(cur, src);
    const size_t ob = (size_t)row * Tgt;
    float oid, osc;
    if (lane < Ccand) {
        oid = (float)my_id;
        osc = my_s;
    } else {
        oid = (float)(int)(511 - (u32)(kk & 511ull));
        osc = __uint_as_float((u32)(kk >> 32));
    }
    out_ids[ob + lane]    = oid;
    out_scores[ob + lane] = osc;
}

extern "C" void kernel_launch(void* const* d_in, const int* in_sizes, int n_in,
                              void* d_out, int out_size, void* d_ws, size_t ws_size,
                              hipStream_t stream) {
    const int*   ids    = (const int*)d_in[0];
    const float* scores = (const float*)d_in[1];
    const float* cooc   = (const float*)d_in[2];
    int B = in_sizes[0] / Ccand;
    float* out_ids    = (float*)d_out;
    float* out_scores = out_ids + (size_t)B * Tgt;
    int blocks = (B + 3) / 4;
    hipLaunchKernelGGL(cooc_expand, dim3(blocks), dim3(256), 0, stream,
                       ids, scores, cooc, out_ids, out_scores, B);
}

// Round 5
// 203.481 us; speedup vs baseline: 1.0042x; 1.0042x over previous
//
#include <hip/hip_runtime.h>
#include <stdint.h>

typedef unsigned long long u64;
typedef unsigned int u32;
typedef float vf2 __attribute__((ext_vector_type(2)));

constexpr int Ccand = 32;   // candidates per row
constexpr int Evoc  = 512;  // vocab size
constexpr int Tgt   = 64;   // target_size

// ---- xor-partner exchange (round-2 known-good forms) ----------------------
// j=1,2  : DPP quad_perm  (pure VALU, no LDS, no address math)
// j=4..16: ds_swizzle with immediate xor pattern (no address VALU)
// j=32   : bpermute-based __shfl_xor (crosses the 32-lane swizzle boundary)
template<int J>
__device__ __forceinline__ int shx32(int x) {
    if constexpr (J == 1)       return __builtin_amdgcn_update_dpp(0, x, 0xB1, 0xF, 0xF, true); // quad_perm [1,0,3,2]
    else if constexpr (J == 2)  return __builtin_amdgcn_update_dpp(0, x, 0x4E, 0xF, 0xF, true); // quad_perm [2,3,0,1]
    else if constexpr (J <= 16) return __builtin_amdgcn_ds_swizzle(x, (J << 10) | 0x1F);        // BitMode xor
    else                        return __shfl_xor(x, J);
}

// bitonic compare-exchange step; direction masks (lane&K2)==0 / (lane&J)==0 are
// 6 distinct values total -> CSE'd into SGPR masks, step is cmp + s_xnor + cndmask
template<int K2, int J>
__device__ __forceinline__ void cas_f32(float& a, int lane) {
    float o = __int_as_float(shx32<J>(__float_as_int(a)));
    bool keepMax = (((lane & K2) == 0) == ((lane & J) == 0));
    bool g = a > o;
    a = (keepMax == g) ? a : o;
}

template<int K2, int J>
__device__ __forceinline__ void cas_u64(u64& a, int lane) {
    int lo = shx32<J>((int)(u32)a);
    int hi = shx32<J>((int)(u32)(a >> 32));
    u64 o = ((u64)(u32)hi << 32) | (u32)lo;
    bool keepMax = (((lane & K2) == 0) == ((lane & J) == 0));
    bool g = a > o;
    a = (keepMax == g) ? a : o;
}

__device__ __forceinline__ void sort64_desc_f32(float& a, int lane) {
    cas_f32<2,1>(a,lane);
    cas_f32<4,2>(a,lane);   cas_f32<4,1>(a,lane);
    cas_f32<8,4>(a,lane);   cas_f32<8,2>(a,lane);   cas_f32<8,1>(a,lane);
    cas_f32<16,8>(a,lane);  cas_f32<16,4>(a,lane);  cas_f32<16,2>(a,lane);  cas_f32<16,1>(a,lane);
    cas_f32<32,16>(a,lane); cas_f32<32,8>(a,lane);  cas_f32<32,4>(a,lane);  cas_f32<32,2>(a,lane);  cas_f32<32,1>(a,lane);
    cas_f32<64,32>(a,lane); cas_f32<64,16>(a,lane); cas_f32<64,8>(a,lane);  cas_f32<64,4>(a,lane);  cas_f32<64,2>(a,lane); cas_f32<64,1>(a,lane);
}

__device__ __forceinline__ void sort64_desc_u64(u64& a, int lane) {
    cas_u64<2,1>(a,lane);
    cas_u64<4,2>(a,lane);   cas_u64<4,1>(a,lane);
    cas_u64<8,4>(a,lane);   cas_u64<8,2>(a,lane);   cas_u64<8,1>(a,lane);
    cas_u64<16,8>(a,lane);  cas_u64<16,4>(a,lane);  cas_u64<16,2>(a,lane);  cas_u64<16,1>(a,lane);
    cas_u64<32,16>(a,lane); cas_u64<32,8>(a,lane);  cas_u64<32,4>(a,lane);  cas_u64<32,2>(a,lane);  cas_u64<32,1>(a,lane);
    cas_u64<64,32>(a,lane); cas_u64<64,16>(a,lane); cas_u64<64,8>(a,lane);  cas_u64<64,4>(a,lane);  cas_u64<64,2>(a,lane); cas_u64<64,1>(a,lane);
}

// reverse low 16 bits: bit t of result = bit (15-t) of x
__device__ __forceinline__ u32 rev16(u32 x) {
    return __builtin_bitreverse32(x) >> 16;
}

// ---- inline-asm load pair: one cooc row half at +0 and +1024 bytes --------
// volatile + early-clobber: the compiler cannot sink, dedupe, or auto-waitcnt
// these (asm defs are untracked by SIInsertWaitcnts) — the ONLY waits in the
// accumulation loop are our explicit counted vmcnt below.
__device__ __forceinline__ void gload2(const float* p, float4& lo, float4& hi) {
    asm volatile("global_load_dwordx4 %0, %2, off\n\t"
                 "global_load_dwordx4 %1, %2, off offset:1024"
                 : "=&v"(lo), "=&v"(hi)
                 : "v"(p));
}
// counted waits + sched fence (rule #18: hipcc hoists register-only FMAs past
// an asm waitcnt unless a sched_barrier(0) pins them)
__device__ __forceinline__ void wait_vm4() {
    asm volatile("s_waitcnt vmcnt(4)" ::);
    __builtin_amdgcn_sched_barrier(0);
}
__device__ __forceinline__ void wait_vm0() {
    asm volatile("s_waitcnt vmcnt(0)" ::);
    __builtin_amdgcn_sched_barrier(0);
}

// One wave (64 lanes) per row. Lane l owns cols {4l..4l+3} and {256+4l..+3}.
__global__ __launch_bounds__(256, 8) void cooc_expand(
    const int* __restrict__ cand_ids,
    const float* __restrict__ cand_scores,
    const float* __restrict__ cooc,
    float* __restrict__ out_ids,
    float* __restrict__ out_scores,
    int B)
{
    const int lane = threadIdx.x & 63;
    const int wid  = threadIdx.x >> 6;
    const int row  = blockIdx.x * 4 + wid;
    __shared__ u64 buf[4][64];     // per-wave 64-slot window (2 KB/block)
    __shared__ u32 maskw[4][16];   // per-wave 512-bit candidate bitmap
    if (row >= B) return;   // never taken (B % 4 == 0); no block barriers used

    // ---- load candidates (lanes 0..31); start the LDS candidate bitmap early ----
    if (lane < 16) maskw[wid][lane] = 0u;
    int   my_id = -1;
    float my_s  = 0.0f;
    if (lane < Ccand) {
        my_id = cand_ids[(size_t)row * Ccand + lane];
        my_s  = cand_scores[(size_t)row * Ccand + lane];
    }
    __threadfence_block();  // zero before or (same-wave LDS ordering)
    if (lane < Ccand)
        atomicOr(&maskw[wid][(u32)my_id >> 5], 1u << (my_id & 31));  // idempotent, dups fine

    // ---- all-pairs id compare, SPLIT across wave halves ------------------
    // lane l<32 compares id_l against j=0..15; lane l+32 compares the SAME
    // id (one shfl_xor) against j=16..31. 16 bpermute broadcasts (DS pipe)
    // instead of 32 readlanes (VALU pipe); one shfl_xor recombines masks.
    int pid = __shfl_xor(my_id, 32);              // lanes>=32: id of lane-32
    int qid = (lane < 32) ? my_id : pid;          // id this lane is responsible for
    const int jb4 = (lane < 32) ? 0 : (16 << 2);  // byte addr base of j-range
    u32 acc_eq = 0u, acc_lt = 0u;
    #pragma unroll
    for (int t = 0; t < 16; ++t) {
        int idj = __builtin_amdgcn_ds_bpermute(jb4 + (t << 2), my_id); // id_{jb+t}
        acc_eq = (acc_eq << 1) | (idj == qid ? 1u : 0u);
        acc_lt = (acc_lt << 1) | (idj <  qid ? 1u : 0u);
    }
    // bit t of rev16(acc) corresponds to j = jb + t
    u32 pk = (rev16(acc_eq) << 16) | rev16(acc_lt);
    u32 op = (u32)__shfl_xor((int)pk, 32);        // partner's masks (other j-half)
    // full 32-bit masks over j=0..31 (valid for lanes<32; unused elsewhere)
    u32 eqm = (pk >> 16) | (op & 0xFFFF0000u);
    u32 ltm = (pk & 0xFFFFu) | (op << 16);

    u32 below = (1u << (lane & 31)) - 1u;
    bool alive = (lane < Ccand) && ((eqm & below) == 0u);  // first occurrence of my_id
    u64 aball = __ballot(alive);
    int m  = __popcll(aball);                 // distinct ids (wave-uniform, >=1)
    int rk = __popc(ltm & (u32)aball);        // rank among distinct ids, ascending id

    // ---- exact duplicate-merge (np.add.at ascending-j order) -------------
    // alive lane's own j is the LOWEST set bit of eqm; start from my_s and
    // add later matches ascending via ffs/bpermute. 0 iterations for ~38%
    // of rows, <=2 for nearly all others.
    float smv = my_s;
    u32 rem = alive ? (eqm & ~(1u << (lane & 31))) : 0u;
    while (__any(rem != 0u)) {
        int j = __ffs(rem) - 1;                // lowest set bit (ascending j)
        float sj = __int_as_float(__builtin_amdgcn_ds_bpermute(j << 2, __float_as_int(my_s)));
        smv += (rem != 0u) ? sj : 0.0f;        // +0.0 exact no-op (smv >= +0)
        rem &= rem - 1u;
    }

    int dst = alive ? rk : ((lane < 32) ? (lane + 32) : lane);
    int sorted_id = __builtin_amdgcn_ds_permute(dst << 2, my_id);
    int sorted_sb = __builtin_amdgcn_ds_permute(dst << 2, __float_as_int(smv));

    // ---- accumulation: ASM-FORCED depth-1 pipeline, ping-pong A/B buffer
    // sets, 2 ids per phase. Loads are volatile asm (compiler cannot sink
    // them — round-4's source-level version was re-sunk, VGPR stayed 28);
    // counted vmcnt(4) keeps the next phase's 4 loads in flight across the
    // FMA block; tail phase waits vmcnt(0) and skips the prefetch entirely
    // (no clamped waste loads). FMA order: id t fully (acc2[0..3]), then
    // id t+1 — identical association to round 2, bit-exact. Tail scores 0:
    // fma(0,·,acc)==acc bit-exact (acc stays >= +0).
    vf2 acc2[4];
    acc2[0] = (vf2){0.f, 0.f}; acc2[1] = (vf2){0.f, 0.f};
    acc2[2] = (vf2){0.f, 0.f}; acc2[3] = (vf2){0.f, 0.f};
    const int l4 = lane << 2;
    const int mm1 = m - 1;
    const float* lbase = cooc + l4;

    auto fma8 = [&](float sv0, const float4& lo0, const float4& hi0,
                    float sv1, const float4& lo1, const float4& hi1) {
        vf2 s_, x_;
        s_[0] = sv0; s_[1] = sv0;
        x_[0] = lo0.x; x_[1] = lo0.y; acc2[0] = __builtin_elementwise_fma(s_, x_, acc2[0]);
        x_[0] = lo0.z; x_[1] = lo0.w; acc2[1] = __builtin_elementwise_fma(s_, x_, acc2[1]);
        x_[0] = hi0.x; x_[1] = hi0.y; acc2[2] = __builtin_elementwise_fma(s_, x_, acc2[2]);
        x_[0] = hi0.z; x_[1] = hi0.w; acc2[3] = __builtin_elementwise_fma(s_, x_, acc2[3]);
        s_[0] = sv1; s_[1] = sv1;
        x_[0] = lo1.x; x_[1] = lo1.y; acc2[0] = __builtin_elementwise_fma(s_, x_, acc2[0]);
        x_[0] = lo1.z; x_[1] = lo1.w; acc2[1] = __builtin_elementwise_fma(s_, x_, acc2[1]);
        x_[0] = hi1.x; x_[1] = hi1.y; acc2[2] = __builtin_elementwise_fma(s_, x_, acc2[2]);
        x_[0] = hi1.z; x_[1] = hi1.w; acc2[3] = __builtin_elementwise_fma(s_, x_, acc2[3]);
    };

    // prologue: ids 0,1 -> A buffers (id1 clamped; its score 0 if m<2)
    float4 A0, A1, A2, A3, B0, B1, B2, B3;
    {
        int pj  = (1 <= mm1) ? 1 : mm1;
        int e0  = __builtin_amdgcn_readlane(sorted_id, 0) & 511;
        int e1  = __builtin_amdgcn_readlane(sorted_id, pj) & 511;
        gload2(lbase + ((size_t)e0 << 9), A0, A1);
        gload2(lbase + ((size_t)e1 << 9), A2, A3);
    }
    float sA0 = __int_as_float(__builtin_amdgcn_readlane(sorted_sb, 0));
    float sA1 = (1 < m) ? __int_as_float(__builtin_amdgcn_readlane(sorted_sb, (1 <= mm1) ? 1 : mm1)) : 0.0f;
    float sB0 = 0.0f, sB1 = 0.0f;
    int t = 0;
    for (;;) {
        // ---- phase A: prefetch ids t+2,t+3 into B; consume A (ids t,t+1) ----
        bool pf = (t + 2 < m);          // wave-uniform
        if (pf) {
            int q1 = (t + 3 <= mm1) ? (t + 3) : mm1;
            int f0 = __builtin_amdgcn_readlane(sorted_id, t + 2) & 511;
            int f1 = __builtin_amdgcn_readlane(sorted_id, q1) & 511;
            sB0 = __int_as_float(__builtin_amdgcn_readlane(sorted_sb, t + 2));
            sB1 = (t + 3 < m) ? __int_as_float(__builtin_amdgcn_readlane(sorted_sb, q1)) : 0.0f;
            gload2(lbase + ((size_t)f0 << 9), B0, B1);
            gload2(lbase + ((size_t)f1 << 9), B2, B3);
            wait_vm4();                 // A complete; B's 4 loads stay in flight
        } else {
            wait_vm0();
        }
        fma8(sA0, A0, A1, sA1, A2, A3);
        if (!pf) break;
        t += 2;
        // ---- phase B: prefetch ids t+2,t+3 into A; consume B ----
        pf = (t + 2 < m);
        if (pf) {
            int q1 = (t + 3 <= mm1) ? (t + 3) : mm1;
            int f0 = __builtin_amdgcn_readlane(sorted_id, t + 2) & 511;
            int f1 = __builtin_amdgcn_readlane(sorted_id, q1) & 511;
            sA0 = __int_as_float(__builtin_amdgcn_readlane(sorted_sb, t + 2));
            sA1 = (t + 3 < m) ? __int_as_float(__builtin_amdgcn_readlane(sorted_sb, q1)) : 0.0f;
            gload2(lbase + ((size_t)f0 << 9), A0, A1);
            gload2(lbase + ((size_t)f1 << 9), A2, A3);
            wait_vm4();
        } else {
            wait_vm0();
        }
        fma8(sB0, B0, B1, sB1, B2, B3);
        if (!pf) break;
        t += 2;
    }

    // ---- masked-slot bits from the LDS bitmap (reference: cooc_scores[b,e] = -inf).
    // col c=4l+q -> word l>>3 bit 4(l&7)+q ; col 256+4l+q -> word 8+(l>>3) same bit.
    __threadfence_block();
    u32 wA = maskw[wid][lane >> 3];
    u32 wB = maskw[wid][8 + (lane >> 3)];
    int sh = (lane & 7) << 2;
    u32 mb = ((wA >> sh) & 15u) | (((wB >> sh) & 15u) << 4);

    // ---- original-layout values; masked -> -1.0 (strictly below all) ----
    float v[8];
    v[0] = acc2[0][0]; v[1] = acc2[0][1]; v[2] = acc2[1][0]; v[3] = acc2[1][1];
    v[4] = acc2[2][0]; v[5] = acc2[2][1]; v[6] = acc2[3][0]; v[7] = acc2[3][1];
    #pragma unroll
    for (int j = 0; j < 8; ++j)
        if ((mb >> j) & 1u) v[j] = -1.0f;

    // ---- L32: 32nd largest of per-lane maxima; L32 <= V32 (true 32nd of
    // all 512) and >=32 elements are >= L32, so every top-32 element
    // survives and S_tot >= 32 ----
    float mx8 = v[0];
    #pragma unroll
    for (int j = 1; j < 8; ++j) mx8 = fmaxf(mx8, v[j]);
    float srt = mx8;
    sort64_desc_f32(srt, lane);
    float L32 = __int_as_float(__builtin_amdgcn_readlane(__float_as_int(srt), 31));

    // ---- survivor count + exclusive prefix via ballot/mbcnt (no shfl_up chain) ----
    int cnt = 0;
    #pragma unroll
    for (int j = 0; j < 8; ++j) cnt += (v[j] >= L32) ? 1 : 0;
    int sbase = 0, S_tot = 0;
    #pragma unroll
    for (int b = 0; b < 4; ++b) {
        u64 bal = __ballot(((cnt >> b) & 1) != 0);
        int pc = __builtin_amdgcn_mbcnt_hi((u32)(bal >> 32),
                 __builtin_amdgcn_mbcnt_lo((u32)bal, 0));
        sbase += pc << b;
        S_tot += ((int)__popcll(bal)) << b;
    }

    // ---- chunked scatter + sort + merge-prune over 64-slot windows.
    // Chunk 0 is the whole story for ~99.98% of rows (S_tot <= 64).
    // Keys (valbits<<32 | 511-col) unique; desc u64 order == np stable
    // top-k order (value desc, col asc). ----
    int nchunk = (S_tot + 63) >> 6;   // wave-uniform >= 1
    u64 cur = 0ull;
    #pragma unroll 1
    for (int c = 0; c < nchunk; ++c) {
        const int lo = c << 6;
        // scatter survivors whose slot falls in [lo, lo+64)
        int slot = sbase;
        #pragma unroll
        for (int j = 0; j < 8; ++j) {
            bool s = (v[j] >= L32);
            int  rel = slot - lo;
            if (s && rel >= 0 && rel < 64) {
                int col = (j < 4) ? (l4 + j) : (256 + l4 + (j - 4));
                buf[wid][rel] = ((u64)__float_as_uint(v[j]) << 32) | (u32)(511 - col);
            }
            slot += s ? 1 : 0;
        }
        __threadfence_block();
        u64 nxt = (lo + lane < S_tot) ? buf[wid][lane] : 0ull;
        __threadfence_block();   // reads complete before next chunk's writes
        sort64_desc_u64(nxt, lane);
        if (c == 0) {
            cur = nxt;
        } else {
            u64 o = __shfl_xor(nxt, 63);           // nxt[63-lane]
            cur = (cur >= o) ? cur : o;            // top-64 of 128, bitonic
            cas_u64<64,32>(cur, lane);             // descending cleanup
            cas_u64<64,16>(cur, lane);
            cas_u64<64,8>(cur, lane);
            cas_u64<64,4>(cur, lane);
            cas_u64<64,2>(cur, lane);
            cas_u64<64,1>(cur, lane);
        }
    }
    // lane r now holds rank-r key (r < 32 are the selected top-32)

    // ---- coalesced stores: [orig 32 | selected 32] ----
    int src = (lane >= 32) ? (lane - 32) : 0;
    u64 kk = __shfl(cur, src);
    const size_t ob = (size_t)row * Tgt;
    float oid, osc;
    if (lane < Ccand) {
        oid = (float)my_id;
        osc = my_s;
    } else {
        oid = (float)(int)(511 - (u32)(kk & 511ull));
        osc = __uint_as_float((u32)(kk >> 32));
    }
    out_ids[ob + lane]    = oid;
    out_scores[ob + lane] = osc;
}

extern "C" void kernel_launch(void* const* d_in, const int* in_sizes, int n_in,
                              void* d_out, int out_size, void* d_ws, size_t ws_size,
                              hipStream_t stream) {
    const int*   ids    = (const int*)d_in[0];
    const float* scores = (const float*)d_in[1];
    const float* cooc   = (const float*)d_in[2];
    int B = in_sizes[0] / Ccand;
    float* out_ids    = (float*)d_out;
    float* out_scores = out_ids + (size_t)B * Tgt;
    int blocks = (B + 3) / 4;
    hipLaunchKernelGGL(cooc_expand, dim3(blocks), dim3(256), 0, stream,
                       ids, scores, cooc, out_ids, out_scores, B);
}